// Round 6
// baseline (329.582 us; speedup 1.0000x reference)
//
#include <hip/hip_runtime.h>
#include <limits.h>
#include <math.h>
#include <stdint.h>

#define WOS_ZERO_TOL 1e-6f
#define STRIDE 57   // 57 % 32 odd -> 16 channel rows start on distinct banks

// One wave (64 lanes) per pixel.
// Phase 1 (per nc): lane d owns candidate d (d<27: patch value, d>=27:
//   negated). Stable descending rank via u64 key (ordered_float :: 63-lane)
//   compare — bit-exact vs jnp stable argsort (verified rounds 2/4/5).
//   Rank loop is inline asm pinned to 3 VALU/iter (readlane + cmp_u64 + addc;
//   key low word built on the scalar pipe). Scatter weight & value into
//   sorted LDS columns s_ws/s_mx[wid][nc][rank] (<=2-way bank alias = free).
// Phase 2 (transposed): lane nc = lane&15 walks all 54 sorted slots once —
//   sequential f32 adds, identical association order to np.cumsum.
//   rstar = last r with (w!=0 && acc<=bias), fallback first-nz.
__global__ __launch_bounds__(256) void wos_kernel(
    const float* __restrict__ x,       // (8,3,64,64)
    const float* __restrict__ mask,    // (16,54)
    const float* __restrict__ weight,  // (16,54)
    const float* __restrict__ bias,    // (16,1)
    float* __restrict__ out)           // flat: [pixel*16 + nc]
{
    __shared__ float s_ws[4][16][STRIDE];
    __shared__ float s_mx[4][16][STRIDE];

    const int lane = threadIdx.x & 63;
    const int wid  = threadIdx.x >> 6;
    const int p    = blockIdx.x * 4 + wid;   // pixel in [0, 32768)
    const int b    = p >> 12;
    const int l    = p & 4095;
    const int h    = l >> 6;
    const int w    = l & 63;

    // Gather this lane's patch value (zero padding at borders).
    float inp = 0.0f;
    if (lane < 54) {
        int dm  = (lane < 27) ? lane : lane - 27;
        int c   = dm / 9;
        int rem = dm - 9 * c;
        int di  = rem / 3;
        int dj  = rem - 3 * di;
        int hh  = h + di - 1;
        int ww  = w + dj - 1;
        if (hh >= 0 && hh < 64 && ww >= 0 && ww < 64) {
            float v = x[((b * 3 + c) << 12) + (hh << 6) + ww];
            inp = (lane < 27) ? v : -v;
        }
    }

    const uint32_t inv_lane = (uint32_t)(63 - lane);

    // ---- Phase 1: rank + scatter into sorted coordinates ----
    #pragma unroll 1
    for (int nc = 0; nc < 16; ++nc) {
        float mk   = (lane < 54) ? mask[nc * 54 + lane]   : 0.0f;
        float wv   = (lane < 54) ? weight[nc * 54 + lane] : 0.0f;
        float mxv  = (lane < 54) ? (inp + mk) : -INFINITY;
        float wsel = (wv > WOS_ZERO_TOL) ? wv : 0.0f;

        // Order-preserving uint32 map of float order (no NaNs here).
        int      bits = __float_as_int(mxv);
        uint32_t ob   = (uint32_t)(bits ^ ((bits >> 31) | 0x80000000));
        // 64-bit stable key: value major, (63-lane) minor -> distinct keys,
        // strict > reproduces jnp's stable descending argsort exactly.
        uint64_t myk  = ((uint64_t)ob << 32) | inv_lane;

        // rank = #{dp in 0..53 : key_dp > key_mine}, 3 VALU / iteration.
        // s20 = dp, s22 = 63-dp (key low), s23 = ob_dp (key high).
        // readlane->cmp gap covered by the interposed s_sub.
        uint32_t rank;
        asm volatile(
            "s_mov_b32 s20, 0\n\t"
            "v_mov_b32 %[rk], 0\n\t"
            "1:\n\t"
            "v_readlane_b32 s23, %[ob], s20\n\t"
            "s_sub_u32 s22, 63, s20\n\t"
            "v_cmp_gt_u64 vcc, s[22:23], %[myk]\n\t"
            "v_addc_co_u32 %[rk], vcc, 0, %[rk], vcc\n\t"
            "s_add_u32 s20, s20, 1\n\t"
            "s_cmp_lt_u32 s20, 54\n\t"
            "s_cbranch_scc1 1b\n\t"
            : [rk] "=&v"(rank)
            : [ob] "v"(ob), [myk] "v"(myk)
            : "s20", "s22", "s23", "vcc", "scc");

        // Active lanes have ranks 0..53 (they all beat the idle keys only
        // via broadcasts 0..53, which exclude idle lanes entirely).
        if (lane < 54) {
            s_ws[wid][nc][rank] = wsel;
            s_mx[wid][nc][rank] = mxv;
        }
    }
    // Same-wave LDS RAW: compiler inserts the lgkmcnt wait; no barrier needed
    // (each wave touches only its own [wid] slice).

    // ---- Phase 2: transposed sequential scan, lane = channel ----
    {
        const int   nc = lane & 15;       // lanes 16..63 run redundant copies
        const float bv = bias[nc];
        float acc   = 0.0f;
        int   rstar = -1;
        int   fnz   = 64;
        #pragma unroll
        for (int r = 0; r < 54; ++r) {
            float wr = s_ws[wid][nc][r];
            acc += wr;                                   // exact np.cumsum order
            bool nz = (__float_as_int(wr) != 0);
            rstar = (nz && acc <= bv) ? r : rstar;       // last nz with acc<=bias
            fnz   = (nz && r < fnz)   ? r : fnz;         // first nz (fallback)
        }
        if (rstar < 0) rstar = (fnz < 54) ? fnz : 0;     // fallback (rare)
        float ans = s_mx[wid][nc][rstar];
        if (lane < 16) out[p * 16 + lane] = ans;
    }
}

extern "C" void kernel_launch(void* const* d_in, const int* in_sizes, int n_in,
                              void* d_out, int out_size, void* d_ws, size_t ws_size,
                              hipStream_t stream) {
    const float* x      = (const float*)d_in[0];
    const float* mask   = (const float*)d_in[1];
    const float* weight = (const float*)d_in[2];
    const float* bias   = (const float*)d_in[3];
    float* out = (float*)d_out;

    // 32768 pixels, 4 waves (pixels) per 256-thread block -> 8192 blocks
    wos_kernel<<<dim3(8192), dim3(256), 0, stream>>>(x, mask, weight, bias, out);
}

// Round 7
// 248.671 us; speedup vs baseline: 1.3254x; 1.3254x over previous
//
#include <hip/hip_runtime.h>
#include <limits.h>
#include <math.h>
#include <stdint.h>

#define WOS_ZERO_TOL 1e-6f
#define STRIDE 57   // odd stride: 16 channel rows start on distinct banks

// One wave (64 lanes) per pixel.
// Phase 1 (per nc): lane d owns candidate d (d<27: patch value, d>=27:
//   negated). Stable descending rank via u64 key (ordered_float :: 63-lane)
//   — bit-exact vs jnp stable argsort (verified rounds 2/4/5/6). The rank
//   loop is FULLY UNROLLED inline asm: per iteration 3.5 VALU + 1 SALU
//   (readlane const-lane -> sgpr high word; s_mov const low word; u64 cmp
//   into an sgpr pair; cndmask 0/1; add3 folds two bits). Two interleaved
//   chains (s[8:9] / s[10:11]) kill carry serialization; no branches.
// Scatter weight & value into sorted LDS columns s_ws/s_mx[wid][nc][rank]
//   (ranks 0..53 distinct => <=2-way bank alias, free on CDNA4).
// Phase 2 (transposed): lane nc = lane&15 walks the 54 sorted slots once —
//   sequential f32 adds, association order identical to np.cumsum.
//   rstar = last r with (w!=0 && acc<=bias), fallback first-nz.
__global__ __launch_bounds__(256) void wos_kernel(
    const float* __restrict__ x,       // (8,3,64,64)
    const float* __restrict__ mask,    // (16,54)
    const float* __restrict__ weight,  // (16,54)
    const float* __restrict__ bias,    // (16,1)
    float* __restrict__ out)           // flat: [pixel*16 + nc]
{
    __shared__ float s_ws[4][16][STRIDE];
    __shared__ float s_mx[4][16][STRIDE];

    const int lane = threadIdx.x & 63;
    const int wid  = threadIdx.x >> 6;
    const int p    = blockIdx.x * 4 + wid;   // pixel in [0, 32768)
    const int b    = p >> 12;
    const int l    = p & 4095;
    const int h    = l >> 6;
    const int w    = l & 63;

    // Gather this lane's patch value (zero padding at borders).
    float inp = 0.0f;
    if (lane < 54) {
        int dm  = (lane < 27) ? lane : lane - 27;
        int c   = dm / 9;
        int rem = dm - 9 * c;
        int di  = rem / 3;
        int dj  = rem - 3 * di;
        int hh  = h + di - 1;
        int ww  = w + dj - 1;
        if (hh >= 0 && hh < 64 && ww >= 0 && ww < 64) {
            float v = x[((b * 3 + c) << 12) + (hh << 6) + ww];
            inp = (lane < 27) ? v : -v;
        }
    }

    const uint32_t inv_lane = (uint32_t)(63 - lane);

// Two iterations (broadcast lanes DP0, DP1; key low words LO0=63-DP0,
// LO1=63-DP1). 7 VALU + 2 SALU, branch-free, hazard gaps >= 3 for
// readlane->cmp, independent sgpr carry pairs for the two sub-chains.
#define RANK2(DP0, DP1, LO0, LO1) \
    "v_readlane_b32 s23, %[ob], " #DP0 "\n\t" \
    "v_readlane_b32 s25, %[ob], " #DP1 "\n\t" \
    "s_mov_b32 s22, " #LO0 "\n\t" \
    "s_mov_b32 s24, " #LO1 "\n\t" \
    "v_cmp_gt_u64 s[8:9], s[22:23], %[k]\n\t" \
    "v_cmp_gt_u64 s[10:11], s[24:25], %[k]\n\t" \
    "v_cndmask_b32 %[b0], 0, 1, s[8:9]\n\t" \
    "v_cndmask_b32 %[b1], 0, 1, s[10:11]\n\t" \
    "v_add3_u32 %[rk], %[rk], %[b0], %[b1]\n\t"

    // ---- Phase 1: rank + scatter into sorted coordinates ----
    #pragma unroll 1
    for (int nc = 0; nc < 16; ++nc) {
        float mk   = (lane < 54) ? mask[nc * 54 + lane]   : 0.0f;
        float wv   = (lane < 54) ? weight[nc * 54 + lane] : 0.0f;
        float mxv  = (lane < 54) ? (inp + mk) : -INFINITY;
        float wsel = (wv > WOS_ZERO_TOL) ? wv : 0.0f;

        // Order-preserving uint32 map of float order (no NaNs here).
        int      bits = __float_as_int(mxv);
        uint32_t ob   = (uint32_t)(bits ^ ((bits >> 31) | 0x80000000));
        // 64-bit stable key: value major, (63-lane) minor -> distinct keys,
        // strict > reproduces jnp's stable descending argsort exactly.
        uint64_t myk  = ((uint64_t)ob << 32) | inv_lane;

        uint32_t rank, tb0, tb1;
        asm volatile(
            "v_mov_b32 %[rk], 0\n\t"
            RANK2( 0,  1, 63, 62)
            RANK2( 2,  3, 61, 60)
            RANK2( 4,  5, 59, 58)
            RANK2( 6,  7, 57, 56)
            RANK2( 8,  9, 55, 54)
            RANK2(10, 11, 53, 52)
            RANK2(12, 13, 51, 50)
            RANK2(14, 15, 49, 48)
            RANK2(16, 17, 47, 46)
            RANK2(18, 19, 45, 44)
            RANK2(20, 21, 43, 42)
            RANK2(22, 23, 41, 40)
            RANK2(24, 25, 39, 38)
            RANK2(26, 27, 37, 36)
            RANK2(28, 29, 35, 34)
            RANK2(30, 31, 33, 32)
            RANK2(32, 33, 31, 30)
            RANK2(34, 35, 29, 28)
            RANK2(36, 37, 27, 26)
            RANK2(38, 39, 25, 24)
            RANK2(40, 41, 23, 22)
            RANK2(42, 43, 21, 20)
            RANK2(44, 45, 19, 18)
            RANK2(46, 47, 17, 16)
            RANK2(48, 49, 15, 14)
            RANK2(50, 51, 13, 12)
            RANK2(52, 53, 11, 10)
            : [rk] "=&v"(rank), [b0] "=&v"(tb0), [b1] "=&v"(tb1)
            : [ob] "v"(ob), [k] "v"(myk)
            : "s8", "s9", "s10", "s11", "s22", "s23", "s24", "s25");

        // Active lanes get distinct ranks 0..53 (broadcasts cover only
        // real candidates 0..53; idle lanes are excluded entirely).
        if (lane < 54) {
            s_ws[wid][nc][rank] = wsel;
            s_mx[wid][nc][rank] = mxv;
        }
    }
    // Same-wave LDS RAW: compiler inserts the lgkmcnt wait; no barrier needed
    // (each wave touches only its own [wid] slice).

    // ---- Phase 2: transposed sequential scan, lane = channel ----
    {
        const int   nc = lane & 15;       // lanes 16..63 run redundant copies
        const float bv = bias[nc];
        float acc   = 0.0f;
        int   rstar = -1;
        int   fnz   = 64;
        #pragma unroll
        for (int r = 0; r < 54; ++r) {
            float wr = s_ws[wid][nc][r];
            acc += wr;                                   // exact np.cumsum order
            bool nz = (__float_as_int(wr) != 0);
            rstar = (nz && acc <= bv) ? r : rstar;       // last nz with acc<=bias
            fnz   = (nz && r < fnz)   ? r : fnz;         // first nz (fallback)
        }
        if (rstar < 0) rstar = (fnz < 54) ? fnz : 0;     // fallback (rare)
        float ans = s_mx[wid][nc][rstar];
        if (lane < 16) out[p * 16 + lane] = ans;
    }
}

extern "C" void kernel_launch(void* const* d_in, const int* in_sizes, int n_in,
                              void* d_out, int out_size, void* d_ws, size_t ws_size,
                              hipStream_t stream) {
    const float* x      = (const float*)d_in[0];
    const float* mask   = (const float*)d_in[1];
    const float* weight = (const float*)d_in[2];
    const float* bias   = (const float*)d_in[3];
    float* out = (float*)d_out;

    // 32768 pixels, 4 waves (pixels) per 256-thread block -> 8192 blocks
    wos_kernel<<<dim3(8192), dim3(256), 0, stream>>>(x, mask, weight, bias, out);
}

// Round 8
// 202.168 us; speedup vs baseline: 1.6302x; 1.2300x over previous
//
#include <hip/hip_runtime.h>
#include <limits.h>
#include <math.h>
#include <stdint.h>

#define WOS_ZERO_TOL 1e-6f
#define STRIDE 57   // odd stride: 16 channel rows start on distinct banks

// One wave (64 lanes) per pixel.
// Phase 1 (per nc): lane d owns candidate d (d<27: patch value, d>=27:
//   negated). Stable descending rank via u64 key (ordered_float :: 63-lane)
//   — bit-exact vs jnp stable argsort (verified rounds 2/4/5/6/7).
//   NEW: broadcast goes through LDS, not the SGPR file. Each lane writes its
//   full u64 key to s_key[wid][lane]; the rank loop reads keys dp=0..53 at
//   wave-uniform addresses (hardware broadcast, conflict-free, LDS pipe).
//   Per dp the VALU cost is exactly v_cmp_gt_u64 vcc + v_addc — no
//   v_readlane / SGPR-pair materialization (measured ~6 extra cyc each on
//   CDNA4 for VALU<->SGPR ops; that was rounds 5-7's hidden tax).
// Scatter weight & value into sorted LDS columns s_ws/s_mx[wid][nc][rank]
//   (ranks 0..53 distinct => <=2-way bank alias, free on CDNA4).
// Phase 2 (transposed): lane nc = lane&15 walks the 54 sorted slots once —
//   sequential f32 adds, association order identical to np.cumsum.
//   rstar = last r with (w!=0 && acc<=bias), fallback first-nz.
__global__ __launch_bounds__(256) void wos_kernel(
    const float* __restrict__ x,       // (8,3,64,64)
    const float* __restrict__ mask,    // (16,54)
    const float* __restrict__ weight,  // (16,54)
    const float* __restrict__ bias,    // (16,1)
    float* __restrict__ out)           // flat: [pixel*16 + nc]
{
    __shared__ float s_ws[4][16][STRIDE];
    __shared__ float s_mx[4][16][STRIDE];
    __shared__ unsigned long long s_key[4][64];

    const int lane = threadIdx.x & 63;
    const int wid  = threadIdx.x >> 6;
    const int p    = blockIdx.x * 4 + wid;   // pixel in [0, 32768)
    const int b    = p >> 12;
    const int l    = p & 4095;
    const int h    = l >> 6;
    const int w    = l & 63;

    // Gather this lane's patch value (zero padding at borders).
    float inp = 0.0f;
    if (lane < 54) {
        int dm  = (lane < 27) ? lane : lane - 27;
        int c   = dm / 9;
        int rem = dm - 9 * c;
        int di  = rem / 3;
        int dj  = rem - 3 * di;
        int hh  = h + di - 1;
        int ww  = w + dj - 1;
        if (hh >= 0 && hh < 64 && ww >= 0 && ww < 64) {
            float v = x[((b * 3 + c) << 12) + (hh << 6) + ww];
            inp = (lane < 27) ? v : -v;
        }
    }

    const uint32_t inv_lane = (uint32_t)(63 - lane);

    // ---- Phase 1: rank via LDS-broadcast key compares + scatter ----
    #pragma unroll 1
    for (int nc = 0; nc < 16; ++nc) {
        float mk   = (lane < 54) ? mask[nc * 54 + lane]   : 0.0f;
        float wv   = (lane < 54) ? weight[nc * 54 + lane] : 0.0f;
        float mxv  = (lane < 54) ? (inp + mk) : -INFINITY;
        float wsel = (wv > WOS_ZERO_TOL) ? wv : 0.0f;

        // Order-preserving uint32 map of float order (no NaNs here).
        int      bits = __float_as_int(mxv);
        uint32_t ob   = (uint32_t)(bits ^ ((bits >> 31) | 0x80000000));
        // 64-bit stable key: value major, (63-lane) minor -> distinct keys,
        // strict > reproduces jnp's stable descending argsort exactly.
        uint64_t myk  = ((uint64_t)ob << 32) | inv_lane;

        // Publish key; same-wave RAW/WAR ordering is enforced by in-order
        // per-wave LDS + compiler lgkmcnt waits (each wave owns slice [wid]).
        s_key[wid][lane] = myk;

        // rank = #{dp in 0..53 : key_dp > key_mine}. Uniform-address LDS
        // reads broadcast; VALU per dp = v_cmp_gt_u64 vcc + v_addc.
        uint32_t rank = 0;
        #pragma unroll
        for (int dp = 0; dp < 54; ++dp) {
            rank += (s_key[wid][dp] > myk) ? 1u : 0u;
        }

        // Active lanes get distinct ranks 0..53 (broadcasts cover only real
        // candidates; idle lanes' tiny keys never exceed real keys anyway).
        if (lane < 54) {
            s_ws[wid][nc][rank] = wsel;
            s_mx[wid][nc][rank] = mxv;
        }
    }

    // ---- Phase 2: transposed sequential scan, lane = channel ----
    {
        const int   nc = lane & 15;       // lanes 16..63 run redundant copies
        const float bv = bias[nc];
        float acc   = 0.0f;
        int   rstar = -1;
        int   fnz   = 64;
        #pragma unroll
        for (int r = 0; r < 54; ++r) {
            float wr = s_ws[wid][nc][r];
            acc += wr;                                   // exact np.cumsum order
            bool nz = (__float_as_int(wr) != 0);
            rstar = (nz && acc <= bv) ? r : rstar;       // last nz with acc<=bias
            fnz   = (nz && r < fnz)   ? r : fnz;         // first nz (fallback)
        }
        if (rstar < 0) rstar = (fnz < 54) ? fnz : 0;     // fallback (rare)
        float ans = s_mx[wid][nc][rstar];
        if (lane < 16) out[p * 16 + lane] = ans;
    }
}

extern "C" void kernel_launch(void* const* d_in, const int* in_sizes, int n_in,
                              void* d_out, int out_size, void* d_ws, size_t ws_size,
                              hipStream_t stream) {
    const float* x      = (const float*)d_in[0];
    const float* mask   = (const float*)d_in[1];
    const float* weight = (const float*)d_in[2];
    const float* bias   = (const float*)d_in[3];
    float* out = (float*)d_out;

    // 32768 pixels, 4 waves (pixels) per 256-thread block -> 8192 blocks
    wos_kernel<<<dim3(8192), dim3(256), 0, stream>>>(x, mask, weight, bias, out);
}